// Round 2
// baseline (284.156 us; speedup 1.0000x reference)
//
#include <hip/hip_runtime.h>
#include <hip/hip_bf16.h>

typedef __bf16 bf16x8 __attribute__((ext_vector_type(8)));
typedef float  f32x4  __attribute__((ext_vector_type(4)));

#define NHEAD 5

// ---------------- kernel 0: x fp32 [b][c][d][hw] -> xbf bf16 [ls][p][c] ----------------
__global__ __launch_bounds__(256) void k0_xpose(const float* __restrict__ x,
                                                __bf16* __restrict__ xbf,
                                                int slice_base) {
  int blk = blockIdx.x;
  int ls = blk >> 4;           // local slice in chunk
  int pt = blk & 15;           // 256-position tile
  int g  = slice_base + ls;
  int b = g >> 3, d = g & 7;
  __shared__ __attribute__((aligned(16))) float xs[64][257];
  const int t = threadIdx.x;
  const int wv = t >> 6, l = t & 63;
  const float* xbase = x + (((size_t)b * 64) * 8 + d) * 4096 + pt * 256;
  for (int i = 0; i < 16; ++i) {
    int row = i * 4 + wv;
    int col = l * 4;
    float4 v = *(const float4*)(xbase + (size_t)row * 32768 + col);
    xs[row][col + 0] = v.x; xs[row][col + 1] = v.y;
    xs[row][col + 2] = v.z; xs[row][col + 3] = v.w;
  }
  __syncthreads();
  for (int i = 0; i < 8; ++i) {
    int chunk = i * 256 + t;
    int p = chunk >> 3, cb = chunk & 7;
    bf16x8 o;
    for (int j = 0; j < 8; ++j) o[j] = (__bf16)xs[cb * 8 + j][p];
    *(bf16x8*)(xbf + ((size_t)ls * 4096 + pt * 256 + p) * 64 + cb * 8) = o;
  }
}

// ---------------- fused kernel: projection (12 rows) + 4 attentions ----------------
// block = 512 threads (8 waves); grid = 80 * sc blocks (XCD-chunk swizzled)
__global__ __launch_bounds__(512) void k1_fused(const __bf16* __restrict__ xbf,
                                                const float* __restrict__ x,
                                                const float* __restrict__ W,
                                                const float* __restrict__ bias,
                                                const float* __restrict__ gamma,
                                                float* __restrict__ out,
                                                int slice_base) {
  // LDS: 2304 + 64(pad to 128) + 65536 + 36864 + 32768 = ~137.5 KB -> 1 block/CU
  __shared__ __attribute__((aligned(16))) __bf16 wl[16 * 72];     // W tile [o_l][c]
  __shared__ float blds[32];                                      // bias (16 used)
  __shared__ __attribute__((aligned(16))) __bf16 qk[8][4096];     // Q(0..3),K(4..7) XOR-swz
  __shared__ __attribute__((aligned(16))) __bf16 vt[4][64 * 72];  // V^T [cl][w][j], pad 72
  __shared__ __attribute__((aligned(16))) __bf16 att[4][4096];    // P [cl][i][j] XOR-swz

  // XCD-chunked bijective swizzle: contiguous slices per XCD for L2 reuse of xbf
  int nwg = gridDim.x;                 // 80*sc, always % 8 == 0
  int bid = blockIdx.x;
  int nb = (bid & 7) * (nwg >> 3) + (bid >> 3);
  int ls = nb / 80;
  int r  = nb % 80;
  int n  = r >> 4;                     // head
  int c0 = (r & 15) * 4;               // channel group base
  int g = slice_base + ls;
  int b = g >> 3, d = g & 7;

  const int t = threadIdx.x;
  const int wv = t >> 6, l = t & 63, lr = l & 15, g4 = l >> 4;

  // ---- stage W rows (q,k,v) x (c0..c0+3) as [16][72] bf16, rows 12..15 zero ----
  for (int e = t; e < 1024; e += 512) {
    int row = e >> 6, c = e & 63;
    float v = 0.f;
    if (row < 12) v = W[(size_t)(n * 192 + (row >> 2) * 64 + c0 + (row & 3)) * 64 + c];
    wl[row * 72 + c] = (__bf16)v;
  }
  if (t < 16) blds[t] = (t < 12) ? bias[n * 192 + (t >> 2) * 64 + c0 + (t & 3)] : 0.f;
  __syncthreads();

  bf16x8 wa0 = *(const bf16x8*)(wl + lr * 72 + g4 * 8);
  bf16x8 wa1 = *(const bf16x8*)(wl + lr * 72 + 32 + g4 * 8);
  float bv[4];
  for (int rr = 0; rr < 4; ++rr) bv[rr] = blds[4 * g4 + rr];

  const __bf16* xs = xbf + (size_t)ls * 262144;
  const f32x4 zero4 = {0.f, 0.f, 0.f, 0.f};

  // ---- projection: wave wv covers p in [wv*512, wv*512+512), 2 passes of 256 ----
  for (int h = 0; h < 2; ++h) {
    int pbase = wv * 512 + h * 256;
    f32x4 acc[16];
#pragma unroll
    for (int f = 0; f < 16; ++f) acc[f] = zero4;
#pragma unroll
    for (int f = 0; f < 16; ++f) {
      const __bf16* bp = xs + (size_t)(pbase + f * 16 + lr) * 64;
      bf16x8 b0 = *(const bf16x8*)(bp + g4 * 8);
      bf16x8 b1 = *(const bf16x8*)(bp + 32 + g4 * 8);
      acc[f] = __builtin_amdgcn_mfma_f32_16x16x32_bf16(wa0, b0, acc[f], 0, 0, 0);
      acc[f] = __builtin_amdgcn_mfma_f32_16x16x32_bf16(wa1, b1, acc[f], 0, 0, 0);
    }
    // epilogue: lane holds p = pbase + f*16 + lr, rows 4*g4..4*g4+3
#pragma unroll
    for (int f = 0; f < 16; ++f) {
      int p = pbase + f * 16 + lr;
      int i = p >> 6, w = p & 63;
      if (g4 == 0) {        // Q channels rr
#pragma unroll
        for (int rr = 0; rr < 4; ++rr)
          qk[rr][(i * 64 + w) ^ ((i & 7) << 3)] = (__bf16)(acc[f][rr] + bv[rr]);
      } else if (g4 == 1) { // K
#pragma unroll
        for (int rr = 0; rr < 4; ++rr)
          qk[4 + rr][(i * 64 + w) ^ ((i & 7) << 3)] = (__bf16)(acc[f][rr] + bv[rr]);
      } else if (g4 == 2) { // V -> transposed vt[cl][w][j]
#pragma unroll
        for (int rr = 0; rr < 4; ++rr)
          vt[rr][w * 72 + i] = (__bf16)(acc[f][rr] + bv[rr]);
      }
    }
  }
  __syncthreads();

  // ---- attention: wave -> channel cl = wv>>1, i-half i0 = (wv&1)*32 ----
  const int cl = wv >> 1;
  const int i0 = (wv & 1) * 32;

  // sim[i][j] = sum_w K[i][w] Q[j][w]
  f32x4 sacc[2][4];
#pragma unroll
  for (int ii = 0; ii < 2; ++ii)
#pragma unroll
    for (int jt = 0; jt < 4; ++jt) sacc[ii][jt] = zero4;
  bf16x8 ka[2][2];
#pragma unroll
  for (int ii = 0; ii < 2; ++ii) {
    int ia = i0 + ii * 16 + lr;
    ka[ii][0] = *(const bf16x8*)(&qk[4 + cl][(ia * 64 + g4 * 8) ^ ((ia & 7) << 3)]);
    ka[ii][1] = *(const bf16x8*)(&qk[4 + cl][(ia * 64 + 32 + g4 * 8) ^ ((ia & 7) << 3)]);
  }
#pragma unroll
  for (int jt = 0; jt < 4; ++jt) {
    int ja = jt * 16 + lr;
    bf16x8 qb0 = *(const bf16x8*)(&qk[cl][(ja * 64 + g4 * 8) ^ ((ja & 7) << 3)]);
    bf16x8 qb1 = *(const bf16x8*)(&qk[cl][(ja * 64 + 32 + g4 * 8) ^ ((ja & 7) << 3)]);
#pragma unroll
    for (int ii = 0; ii < 2; ++ii) {
      sacc[ii][jt] = __builtin_amdgcn_mfma_f32_16x16x32_bf16(ka[ii][0], qb0, sacc[ii][jt], 0, 0, 0);
      sacc[ii][jt] = __builtin_amdgcn_mfma_f32_16x16x32_bf16(ka[ii][1], qb1, sacc[ii][jt], 0, 0, 0);
    }
  }

  // softmax over j (spread across jt frags x 16 lanes)
  float pr[2][4][4];
#pragma unroll
  for (int ii = 0; ii < 2; ++ii)
#pragma unroll
    for (int rr = 0; rr < 4; ++rr) {
      float m = fmaxf(fmaxf(sacc[ii][0][rr], sacc[ii][1][rr]),
                      fmaxf(sacc[ii][2][rr], sacc[ii][3][rr]));
#pragma unroll
      for (int dd = 1; dd < 16; dd <<= 1) m = fmaxf(m, __shfl_xor(m, dd));
      float s = 0.f;
#pragma unroll
      for (int jt = 0; jt < 4; ++jt) {
        pr[ii][jt][rr] = __expf(sacc[ii][jt][rr] - m);
        s += pr[ii][jt][rr];
      }
#pragma unroll
      for (int dd = 1; dd < 16; dd <<= 1) s += __shfl_xor(s, dd);
      float inv = 1.0f / s;
#pragma unroll
      for (int jt = 0; jt < 4; ++jt) pr[ii][jt][rr] *= inv;
    }

  // write P (bf16) into att[cl], XOR-swizzled rows
#pragma unroll
  for (int ii = 0; ii < 2; ++ii)
#pragma unroll
    for (int jt = 0; jt < 4; ++jt)
#pragma unroll
      for (int rr = 0; rr < 4; ++rr) {
        int i = i0 + ii * 16 + 4 * g4 + rr;
        int j = jt * 16 + lr;
        att[cl][(i * 64 + j) ^ ((i & 7) << 3)] = (__bf16)pr[ii][jt][rr];
      }
  __syncthreads();

  // pv[i][w] = sum_j att[i][j] V[j][w]
  f32x4 pacc[2][4];
#pragma unroll
  for (int ii = 0; ii < 2; ++ii)
#pragma unroll
    for (int wt = 0; wt < 4; ++wt) pacc[ii][wt] = zero4;
  bf16x8 aa[2][2];
#pragma unroll
  for (int ii = 0; ii < 2; ++ii) {
    int ia = i0 + ii * 16 + lr;
    aa[ii][0] = *(const bf16x8*)(&att[cl][(ia * 64 + g4 * 8) ^ ((ia & 7) << 3)]);
    aa[ii][1] = *(const bf16x8*)(&att[cl][(ia * 64 + 32 + g4 * 8) ^ ((ia & 7) << 3)]);
  }
#pragma unroll
  for (int wt = 0; wt < 4; ++wt) {
    bf16x8 vb0 = *(const bf16x8*)(&vt[cl][(wt * 16 + lr) * 72 + g4 * 8]);
    bf16x8 vb1 = *(const bf16x8*)(&vt[cl][(wt * 16 + lr) * 72 + 32 + g4 * 8]);
#pragma unroll
    for (int ii = 0; ii < 2; ++ii) {
      pacc[ii][wt] = __builtin_amdgcn_mfma_f32_16x16x32_bf16(aa[ii][0], vb0, pacc[ii][wt], 0, 0, 0);
      pacc[ii][wt] = __builtin_amdgcn_mfma_f32_16x16x32_bf16(aa[ii][1], vb1, pacc[ii][wt], 0, 0, 0);
    }
  }

  // epilogue: channel shuffle + gamma + residual
  int c = c0 + cl;
  int o2 = c * NHEAD + n;
  int np = o2 >> 6, fp = o2 & 63;
  int oc = fp * NHEAD + np;
  float gm = gamma[np];
  const float* xp = x + (((size_t)b * 64 + fp) * 8 + d) * 4096;
  float* op = out + (((size_t)b * 320 + oc) * 8 + d) * 4096;
#pragma unroll
  for (int ii = 0; ii < 2; ++ii)
#pragma unroll
    for (int wt = 0; wt < 4; ++wt)
#pragma unroll
      for (int rr = 0; rr < 4; ++rr) {
        int i = i0 + ii * 16 + 4 * g4 + rr;
        int w = wt * 16 + lr;
        int idx = i * 64 + w;
        op[idx] = gm * pacc[ii][wt][rr] + xp[idx];
      }
}

extern "C" void kernel_launch(void* const* d_in, const int* in_sizes, int n_in,
                              void* d_out, int out_size, void* d_ws, size_t ws_size,
                              hipStream_t stream) {
  const float* x     = (const float*)d_in[0];
  const float* W     = (const float*)d_in[1];
  const float* bias  = (const float*)d_in[2];
  const float* gamma = (const float*)d_in[3];
  float* out = (float*)d_out;

  // ws only holds xbf: 512 KB per (b,d) slice
  int S = (int)(ws_size / 524288);
  if (S > 32) S = 32;
  if (S < 1)  S = 1;
  __bf16* xbf = (__bf16*)d_ws;

  for (int sb = 0; sb < 32; sb += S) {
    int sc = 32 - sb; if (sc > S) sc = S;
    k0_xpose<<<16 * sc, 256, 0, stream>>>(x, xbf, sb);
    k1_fused<<<80 * sc, 512, 0, stream>>>(xbf, x, W, bias, gamma, out, sb);
  }
}

// Round 4
// 254.824 us; speedup vs baseline: 1.1151x; 1.1151x over previous
//
#include <hip/hip_runtime.h>
#include <hip/hip_bf16.h>

typedef __bf16 bf16x8 __attribute__((ext_vector_type(8)));
typedef float  f32x4  __attribute__((ext_vector_type(4)));

#define NHEAD 5

// ---------------- kernel 0: x fp32 [b][c][d][hw] -> xbf bf16 [ls][p][c] ----------------
// When sc==32, block placement is XCD-matched to k1_fused's consumer swizzle:
// slice ls is written by blocks with blockIdx%8 == ls>>2 (stays in that XCD's L2).
__global__ __launch_bounds__(256) void k0_xpose(const float* __restrict__ x,
                                                __bf16* __restrict__ xbf,
                                                int slice_base, int sc) {
  int blk = blockIdx.x;
  int ls, pt;
  if (sc == 32) {
    int x8 = blk & 7, idx = blk >> 3;
    ls = x8 * 4 + (idx >> 4);
    pt = idx & 15;
  } else {
    ls = blk >> 4;
    pt = blk & 15;
  }
  int g  = slice_base + ls;
  int b = g >> 3, d = g & 7;
  __shared__ __attribute__((aligned(16))) float xs[64][257];
  const int t = threadIdx.x;
  const int wv = t >> 6, l = t & 63;
  const float* xbase = x + (((size_t)b * 64) * 8 + d) * 4096 + pt * 256;
  for (int i = 0; i < 16; ++i) {
    int row = i * 4 + wv;
    int col = l * 4;
    f32x4 v = __builtin_nontemporal_load((const f32x4*)(xbase + (size_t)row * 32768 + col));
    xs[row][col + 0] = v[0]; xs[row][col + 1] = v[1];
    xs[row][col + 2] = v[2]; xs[row][col + 3] = v[3];
  }
  __syncthreads();
  for (int i = 0; i < 8; ++i) {
    int chunk = i * 256 + t;
    int p = chunk >> 3, cb = chunk & 7;
    bf16x8 o;
    for (int j = 0; j < 8; ++j) o[j] = (__bf16)xs[cb * 8 + j][p];
    *(bf16x8*)(xbf + ((size_t)ls * 4096 + pt * 256 + p) * 64 + cb * 8) = o;
  }
}

// ---------------- fused kernel: projection (12 rows) + 4 attentions ----------------
// 1024 threads (16 waves), 1 block/CU (137.6 KB LDS), 4 waves/SIMD.
__global__ __launch_bounds__(1024, 4) void k1_fused(const __bf16* __restrict__ xbf,
                                                    const float* __restrict__ x,
                                                    const float* __restrict__ W,
                                                    const float* __restrict__ bias,
                                                    const float* __restrict__ gamma,
                                                    float* __restrict__ out,
                                                    int slice_base) {
  __shared__ __attribute__((aligned(16))) __bf16 wl[16 * 72];     // W tile [o_l][c]
  __shared__ float blds[32];                                      // bias (16 used)
  __shared__ __attribute__((aligned(16))) __bf16 qk[8][4096];     // Q(0..3),K(4..7) XOR-swz; later fp32 bounce
  __shared__ __attribute__((aligned(16))) __bf16 vt[4][64 * 72];  // V^T [cl][w][j], pad 72
  __shared__ __attribute__((aligned(16))) __bf16 att[4][4096];    // P [cl][i][j] XOR-swz

  // XCD-chunked bijective swizzle (nwg = 80*sc, always % 8 == 0)
  int nwg = gridDim.x;
  int bid = blockIdx.x;
  int nb = (bid & 7) * (nwg >> 3) + (bid >> 3);
  int ls = nb / 80;
  int r  = nb % 80;
  int n  = r >> 4;                     // head
  int c0 = (r & 15) * 4;               // channel group base
  int g = slice_base + ls;
  int b = g >> 3, d = g & 7;

  const int t = threadIdx.x;
  const int wv = t >> 6, l = t & 63, lr = l & 15, g4 = l >> 4;

  // ---- stage W rows (q,k,v) x (c0..c0+3) as [16][72] bf16, rows 12..15 zero ----
  {
    int row = t >> 6, c = t & 63;
    float v = 0.f;
    if (row < 12) v = W[(size_t)(n * 192 + (row >> 2) * 64 + c0 + (row & 3)) * 64 + c];
    wl[row * 72 + c] = (__bf16)v;
  }
  if (t < 16) blds[t] = (t < 12) ? bias[n * 192 + (t >> 2) * 64 + c0 + (t & 3)] : 0.f;
  __syncthreads();

  bf16x8 wa0 = *(const bf16x8*)(wl + lr * 72 + g4 * 8);
  bf16x8 wa1 = *(const bf16x8*)(wl + lr * 72 + 32 + g4 * 8);
  float bv[4];
#pragma unroll
  for (int rr = 0; rr < 4; ++rr) bv[rr] = blds[4 * g4 + rr];

  const __bf16* xs = xbf + (size_t)ls * 262144;
  const f32x4 zero4 = {0.f, 0.f, 0.f, 0.f};

  // ---- projection: wave wv covers p in [wv*256, wv*256+256) ----
  {
    int pbase = wv * 256;
    f32x4 acc[16];
#pragma unroll
    for (int f = 0; f < 16; ++f) acc[f] = zero4;
    __builtin_amdgcn_s_setprio(1);
#pragma unroll
    for (int f = 0; f < 16; ++f) {
      const __bf16* bp = xs + (size_t)(pbase + f * 16 + lr) * 64;
      bf16x8 b0 = *(const bf16x8*)(bp + g4 * 8);
      bf16x8 b1 = *(const bf16x8*)(bp + 32 + g4 * 8);
      acc[f] = __builtin_amdgcn_mfma_f32_16x16x32_bf16(wa0, b0, acc[f], 0, 0, 0);
      acc[f] = __builtin_amdgcn_mfma_f32_16x16x32_bf16(wa1, b1, acc[f], 0, 0, 0);
    }
    __builtin_amdgcn_s_setprio(0);
    // deposit: lane holds p = pbase + f*16 + lr, rows 4*g4..4*g4+3
#pragma unroll
    for (int f = 0; f < 16; ++f) {
      int p = pbase + f * 16 + lr;
      int i = p >> 6, w = p & 63;
      if (g4 == 0) {        // Q channels rr
#pragma unroll
        for (int rr = 0; rr < 4; ++rr)
          qk[rr][(i * 64 + w) ^ ((i & 7) << 3)] = (__bf16)(acc[f][rr] + bv[rr]);
      } else if (g4 == 1) { // K
#pragma unroll
        for (int rr = 0; rr < 4; ++rr)
          qk[4 + rr][(i * 64 + w) ^ ((i & 7) << 3)] = (__bf16)(acc[f][rr] + bv[rr]);
      } else if (g4 == 2) { // V -> transposed vt[cl][w][j]
#pragma unroll
        for (int rr = 0; rr < 4; ++rr)
          vt[rr][w * 72 + i] = (__bf16)(acc[f][rr] + bv[rr]);
      }
    }
  }

  // ---- prefetch x residual rows (latency hidden under attention) ----
  f32x4 xpre[4];
#pragma unroll
  for (int it = 0; it < 4; ++it) {
    int c = c0 + it;
    int o2 = c * NHEAD + n;
    int fp = o2 & 63;
    const float* xp = x + (((size_t)b * 64 + fp) * 8 + d) * 4096 + t * 4;
    xpre[it] = __builtin_nontemporal_load((const f32x4*)xp);
  }
  __syncthreads();

  // ---- attention: wave -> channel cl = wv>>2, i-tile i0 = (wv&3)*16 ----
  const int cl = wv >> 2;
  const int i0 = (wv & 3) * 16;

  // sim[i][j] = sum_w K[i][w] Q[j][w]
  f32x4 sacc[4];
#pragma unroll
  for (int jt = 0; jt < 4; ++jt) sacc[jt] = zero4;
  bf16x8 ka0, ka1;
  {
    int ia = i0 + lr;
    ka0 = *(const bf16x8*)(&qk[4 + cl][(ia * 64 + g4 * 8) ^ ((ia & 7) << 3)]);
    ka1 = *(const bf16x8*)(&qk[4 + cl][(ia * 64 + 32 + g4 * 8) ^ ((ia & 7) << 3)]);
  }
  __builtin_amdgcn_s_setprio(1);
#pragma unroll
  for (int jt = 0; jt < 4; ++jt) {
    int ja = jt * 16 + lr;
    bf16x8 qb0 = *(const bf16x8*)(&qk[cl][(ja * 64 + g4 * 8) ^ ((ja & 7) << 3)]);
    bf16x8 qb1 = *(const bf16x8*)(&qk[cl][(ja * 64 + 32 + g4 * 8) ^ ((ja & 7) << 3)]);
    sacc[jt] = __builtin_amdgcn_mfma_f32_16x16x32_bf16(ka0, qb0, sacc[jt], 0, 0, 0);
    sacc[jt] = __builtin_amdgcn_mfma_f32_16x16x32_bf16(ka1, qb1, sacc[jt], 0, 0, 0);
  }
  __builtin_amdgcn_s_setprio(0);

  // softmax over j (spread across jt frags x 16 lanes)
  float pr[4][4];
#pragma unroll
  for (int rr = 0; rr < 4; ++rr) {
    float m = fmaxf(fmaxf(sacc[0][rr], sacc[1][rr]), fmaxf(sacc[2][rr], sacc[3][rr]));
#pragma unroll
    for (int dd = 1; dd < 16; dd <<= 1) m = fmaxf(m, __shfl_xor(m, dd));
    float s = 0.f;
#pragma unroll
    for (int jt = 0; jt < 4; ++jt) {
      pr[jt][rr] = __expf(sacc[jt][rr] - m);
      s += pr[jt][rr];
    }
#pragma unroll
    for (int dd = 1; dd < 16; dd <<= 1) s += __shfl_xor(s, dd);
    float inv = 1.0f / s;
#pragma unroll
    for (int jt = 0; jt < 4; ++jt) pr[jt][rr] *= inv;
  }

  // write P (bf16) into att[cl], XOR-swizzled rows
#pragma unroll
  for (int jt = 0; jt < 4; ++jt)
#pragma unroll
    for (int rr = 0; rr < 4; ++rr) {
      int i = i0 + 4 * g4 + rr;
      int j = jt * 16 + lr;
      att[cl][(i * 64 + j) ^ ((i & 7) << 3)] = (__bf16)pr[jt][rr];
    }
  __syncthreads();

  // pv[i][w] = sum_j att[i][j] V[j][w]
  f32x4 pacc[4];
#pragma unroll
  for (int wt = 0; wt < 4; ++wt) pacc[wt] = zero4;
  bf16x8 aa0, aa1;
  {
    int ia = i0 + lr;
    aa0 = *(const bf16x8*)(&att[cl][(ia * 64 + g4 * 8) ^ ((ia & 7) << 3)]);
    aa1 = *(const bf16x8*)(&att[cl][(ia * 64 + 32 + g4 * 8) ^ ((ia & 7) << 3)]);
  }
  __builtin_amdgcn_s_setprio(1);
#pragma unroll
  for (int wt = 0; wt < 4; ++wt) {
    bf16x8 vb0 = *(const bf16x8*)(&vt[cl][(wt * 16 + lr) * 72 + g4 * 8]);
    bf16x8 vb1 = *(const bf16x8*)(&vt[cl][(wt * 16 + lr) * 72 + 32 + g4 * 8]);
    pacc[wt] = __builtin_amdgcn_mfma_f32_16x16x32_bf16(aa0, vb0, pacc[wt], 0, 0, 0);
    pacc[wt] = __builtin_amdgcn_mfma_f32_16x16x32_bf16(aa1, vb1, pacc[wt], 0, 0, 0);
  }
  __builtin_amdgcn_s_setprio(0);

  // bounce PV (fp32) through the dead qk buffer for a vectorized epilogue
  float* fb = (float*)qk;   // 4 ch x 4096 f32 = 64 KB, exact fit
#pragma unroll
  for (int wt = 0; wt < 4; ++wt)
#pragma unroll
    for (int rr = 0; rr < 4; ++rr) {
      int i = i0 + 4 * g4 + rr;
      int w = wt * 16 + lr;
      fb[cl * 4096 + i * 64 + w] = pacc[wt][rr];
    }
  __syncthreads();

  // vectorized epilogue: out = gamma*pv + x, float4 per channel per thread
#pragma unroll
  for (int it = 0; it < 4; ++it) {
    int c = c0 + it;
    int o2 = c * NHEAD + n;
    int np = o2 >> 6, fp = o2 & 63;
    int oc = fp * NHEAD + np;
    float gm = gamma[np];
    f32x4 pv4 = *(const f32x4*)(fb + it * 4096 + t * 4);
    f32x4 o4;
#pragma unroll
    for (int j = 0; j < 4; ++j) o4[j] = gm * pv4[j] + xpre[it][j];
    float* op = out + (((size_t)b * 320 + oc) * 8 + d) * 4096 + t * 4;
    __builtin_nontemporal_store(o4, (f32x4*)op);
  }
}

extern "C" void kernel_launch(void* const* d_in, const int* in_sizes, int n_in,
                              void* d_out, int out_size, void* d_ws, size_t ws_size,
                              hipStream_t stream) {
  const float* x     = (const float*)d_in[0];
  const float* W     = (const float*)d_in[1];
  const float* bias  = (const float*)d_in[2];
  const float* gamma = (const float*)d_in[3];
  float* out = (float*)d_out;

  // ws only holds xbf: 512 KB per (b,d) slice
  int S = (int)(ws_size / 524288);
  if (S > 32) S = 32;
  if (S < 1)  S = 1;
  __bf16* xbf = (__bf16*)d_ws;

  for (int sb = 0; sb < 32; sb += S) {
    int sc = 32 - sb; if (sc > S) sc = S;
    k0_xpose<<<16 * sc, 256, 0, stream>>>(x, xbf, sb, sc);
    k1_fused<<<80 * sc, 1024, 0, stream>>>(xbf, x, W, bias, gamma, out, sb);
  }
}